// Round 3
// baseline (102.558 us; speedup 1.0000x reference)
//
#include <hip/hip_runtime.h>

// QOuter: out_rr[b,i,j] = real[b,i]*real[b,j] + imag[b,i]*imag[b,j]
//         out_ii[b,i,j] = imag[b,i]*real[b,j] - real[b,i]*imag[b,j]
// B=64, N=1024. Outputs concatenated flat: [out_rr (B*N*N), out_ii (B*N*N)].
// Pure store-BW bound: 512 MiB written/call; inputs 512 KB (cache-resident).
// One block per 8-row strip; row vectors in registers; 16 independent
// nontemporal 16B stores per thread. Native vector type for the builtin.

typedef float f32x4 __attribute__((ext_vector_type(4)));

constexpr int B_ = 64;
constexpr int N_ = 1024;
constexpr int ROWS = 8;                 // rows (i values) per block

__global__ __launch_bounds__(256) void qouter_kernel(
    const float* __restrict__ real,
    const float* __restrict__ imag,
    float* __restrict__ out) {
    const int blk = blockIdx.x;                  // 0 .. B*(N/ROWS)-1 = 8191
    const int b   = blk >> 7;                    // blk / (N/ROWS), N/ROWS=128
    const int i0  = (blk & 127) * ROWS;          // first row of this strip
    const int t   = threadIdx.x;                 // 0..255 -> one float4 of row j

    const float* rrow = real + (size_t)b * N_;
    const float* irow = imag + (size_t)b * N_;

    // Row vectors (j-direction), loaded once, live in registers for all 8 rows
    const f32x4 rj = reinterpret_cast<const f32x4*>(rrow)[t];
    const f32x4 ij = reinterpret_cast<const f32x4*>(irow)[t];

    // Output base: float4 index of (b, i0, 4t)
    f32x4* out4    = reinterpret_cast<f32x4*>(out);
    size_t f4_rr   = ((size_t)b * N_ + i0) * (N_ / 4) + t;
    const size_t f4_off_ii = (size_t)B_ * N_ * (N_ / 4);   // out_ii offset

#pragma unroll
    for (int r = 0; r < ROWS; ++r) {
        const float rc = rrow[i0 + r];           // wave-uniform scalar loads
        const float ic = irow[i0 + r];

        f32x4 orr = rc * rj + ic * ij;
        f32x4 oii = ic * rj - rc * ij;

        __builtin_nontemporal_store(orr, out4 + f4_rr);
        __builtin_nontemporal_store(oii, out4 + f4_rr + f4_off_ii);
        f4_rr += N_ / 4;                         // next row i
    }
}

extern "C" void kernel_launch(void* const* d_in, const int* in_sizes, int n_in,
                              void* d_out, int out_size, void* d_ws, size_t ws_size,
                              hipStream_t stream) {
    const float* real = (const float*)d_in[0];
    const float* imag = (const float*)d_in[1];
    float* out = (float*)d_out;

    dim3 grid(B_ * (N_ / ROWS));   // 64 * 128 = 8192 blocks
    dim3 block(256);               // 256 threads x float4 = 1024 columns
    qouter_kernel<<<grid, block, 0, stream>>>(real, imag, out);
}